// Round 10
// baseline (118.544 us; speedup 1.0000x reference)
//
#include <hip/hip_runtime.h>
#include <hip/hip_bf16.h>

#define C 128
#define HW 4096
#define NPOS 65536
#define K 1024
#define MB 256           // positions per block (2x r9: halves codebook re-reads)
#define NBLK (NPOS/MB)   // 256 -> 1 block/CU
#define RS 136           // padded row stride in bf16 elems (272 B)
#define RSB 272          // row stride bytes
#define CHK 64           // codes per chunk
#define NCH (K/CHK)      // 16
#define CHB (CHK*RSB)    // 17408 bytes per chunk

#define ZQ_OFF 0
#define LOSS_OFF 8388608
#define IDX_OFF 8388609
#define COMMIT_OFF 8454145
#define CODE_OFF 8454146

#define WS_IMG_OFF 8192  // bf16 codebook image at d_ws + 8192, 1024*272 B

typedef __bf16 bf16x8 __attribute__((ext_vector_type(8)));
typedef float f32x4 __attribute__((ext_vector_type(4)));
typedef unsigned short u16x8 __attribute__((ext_vector_type(8)));

// Padded bf16 codebook image: row k = 128 bf16 (272B stride),
// fp32 (||e_k||^2 + 1.0) at row byte offset 256. Block 0 zeroes S.
__global__ void vq_prep(const float* __restrict__ emb, unsigned char* __restrict__ img,
                        float* __restrict__ S) {
    int k = blockIdx.x;
    int l = threadIdx.x;            // 64 threads
    if (k == 0 && l == 0) S[0] = 0.0f;
    float v0 = emb[k * C + l];
    float v1 = emb[k * C + 64 + l];
    __hip_bfloat16 h0 = __float2bfloat16(v0);
    __hip_bfloat16 h1 = __float2bfloat16(v1);
    unsigned short* row = (unsigned short*)(img + (size_t)k * RSB);
    row[l] = *(unsigned short*)&h0;
    row[64 + l] = *(unsigned short*)&h1;
    float s = v0 * v0 + v1 * v1;
    #pragma unroll
    for (int off = 32; off; off >>= 1) s += __shfl_down(s, off);
    if (l == 0) *(float*)(img + (size_t)k * RSB + 256) = s + 1.0f;
}

// MB=256, 512 thr / 8 waves (4M x 2N), grid 256 = 1 block/CU.
// Codebook streamed once per block through double-buffered LDS (17 KB/chunk):
// per-dispatch codebook L2 traffic 71 MB vs r9's 256 MB. LDS ~107 KB ->
// 1 block/CU -> 2 waves/EU -> VGPR budget 256 (r9-verified rule), so the
// asm-pinned A fragments (64 VGPRs) stay resident with no spill.
// zt uses an XOR swizzle ^(((row>>2)&7)<<4) on BOTH ds-write and ds-read
// sides (stage writes at pos-stride 4 x 272B all landed in banks {0,16}).
// bbuf stays LINEAR (global_load_lds requires it; its reads are 2-way-free).
__global__ __launch_bounds__(512)
void vq_main(const float* __restrict__ z, const float* __restrict__ emb,
             const unsigned char* __restrict__ img,
             float* __restrict__ out, float* __restrict__ S) {
    __shared__ __align__(16) unsigned short zt[MB * RS];          // 69632 B
    __shared__ __align__(16) unsigned short bbuf[2][CHK * RS];    // 34816 B
    __shared__ unsigned int wbest[2][MB];                         // 2048 B
    __shared__ unsigned short idxs[MB];                           // 512 B
    __shared__ float lred[8];
    // total ~107 KB -> exactly 1 block/CU

    const int t = threadIdx.x;
    const int w = t >> 6;
    const int lane = t & 63;
    const int nn = lane & 15;      // MFMA: A row m / B col n / C col
    const int q = lane >> 4;       // quad
    const int wm = w >> 1;         // M-quarter: positions wm*64..+63
    const int wn = w & 1;          // N-half: codes wn*32..+31 of each chunk

    const int blk = blockIdx.x;
    const int n0g = blk * MB;
    const int b = n0g >> 12;
    const int hw0 = n0g & (HW - 1);
    const float* zg = z + (size_t)b * C * HW + hw0;
    unsigned char* ztb = (unsigned char*)zt;

    // async stage chunk 0 (17 x 1KB split across 8 waves)
    for (int j = w; j < 17; j += 8) {
        __builtin_amdgcn_global_load_lds(
            (const __attribute__((address_space(1))) unsigned int*)(img + j * 1024 + lane * 16),
            (__attribute__((address_space(3))) unsigned int*)((unsigned char*)bbuf[0] + j * 1024),
            16, 0, 0);
    }

    // stage z tile -> LDS bf16 [pos][c], swizzled rows (float4 along pos,
    // register transpose, two 16B ds_writes per position)
    {
        const int pos4 = (t & 63) * 4;
        const int c0 = (t >> 6) * 16;
        float4 fv[16];
        #pragma unroll
        for (int i = 0; i < 16; ++i)
            fv[i] = *(const float4*)&zg[(size_t)(c0 + i) * HW + pos4];
        #pragma unroll
        for (int j = 0; j < 4; ++j) {
            u16x8 p0, p1;
            #pragma unroll
            for (int i = 0; i < 8; ++i) {
                float f0 = (j == 0) ? fv[i].x : (j == 1) ? fv[i].y
                         : (j == 2) ? fv[i].z : fv[i].w;
                float f1 = (j == 0) ? fv[8 + i].x : (j == 1) ? fv[8 + i].y
                         : (j == 2) ? fv[8 + i].z : fv[8 + i].w;
                __hip_bfloat16 h0 = __float2bfloat16(f0);
                __hip_bfloat16 h1 = __float2bfloat16(f1);
                p0[i] = *(unsigned short*)&h0;
                p1[i] = *(unsigned short*)&h1;
            }
            const unsigned int row = pos4 + j;
            const unsigned int sw = ((row >> 2) & 7u) << 4;
            const unsigned int base = row * RSB + c0 * 2;
            *(u16x8*)(ztb + (base ^ sw)) = p0;
            *(u16x8*)(ztb + ((base + 16) ^ sw)) = p1;
        }
    }
    __syncthreads();   // covers zt ds_writes AND chunk-0 global_load_lds drain

    // A fragments: 4 M-tiles x 4 K-steps = 64 VGPRs, pinned resident
    bf16x8 a[4][4];
    #pragma unroll
    for (int mt = 0; mt < 4; ++mt)
        #pragma unroll
        for (int ks = 0; ks < 4; ++ks) {
            const unsigned int row = wm * 64 + mt * 16 + nn;
            const unsigned int sw = ((row >> 2) & 7u) << 4;
            a[mt][ks] = *(bf16x8*)(ztb + ((row * RSB + ks * 64 + q * 16) ^ sw));
            asm volatile("" : "+v"(*(f32x4*)&a[mt][ks]));
        }

    unsigned int best[4][4];
    #pragma unroll
    for (int mt = 0; mt < 4; ++mt)
        #pragma unroll
        for (int r = 0; r < 4; ++r) best[mt][r] = 0xFFFFFFFFu;

    for (int ch = 0; ch < NCH; ++ch) {
        const int p = ch & 1;
        if (ch + 1 < NCH) {   // prefetch next chunk into other buffer
            const unsigned char* src = img + (size_t)(ch + 1) * CHB;
            for (int j = w; j < 17; j += 8) {
                __builtin_amdgcn_global_load_lds(
                    (const __attribute__((address_space(1))) unsigned int*)(src + j * 1024 + lane * 16),
                    (__attribute__((address_space(3))) unsigned int*)((unsigned char*)bbuf[p ^ 1] + j * 1024),
                    16, 0, 0);
            }
        }
        const unsigned short* bb = bbuf[p];

        // wave's 32 codes: two 16-wide N-tiles (linear bbuf, 2-way-free banks)
        const int row0 = wn * 32 + nn;
        const int row1 = row0 + 16;
        bf16x8 bf0[4], bf1[4];
        #pragma unroll
        for (int ks = 0; ks < 4; ++ks) {
            bf0[ks] = *(const bf16x8*)&bb[row0 * RS + ks * 32 + q * 8];
            bf1[ks] = *(const bf16x8*)&bb[row1 * RS + ks * 32 + q * 8];
        }
        const float en0 = *(const float*)&bb[row0 * RS + 128];
        const float en1 = *(const float*)&bb[row1 * RS + 128];
        const unsigned int code0 = (unsigned int)(ch * CHK + wn * 32 + nn);

        f32x4 acc0[4], acc1[4];
        #pragma unroll
        for (int mt = 0; mt < 4; ++mt) {
            acc0[mt] = (f32x4){0.f, 0.f, 0.f, 0.f};
            acc1[mt] = (f32x4){0.f, 0.f, 0.f, 0.f};
        }
        #pragma unroll
        for (int ks = 0; ks < 4; ++ks)
            #pragma unroll
            for (int mt = 0; mt < 4; ++mt) {
                acc0[mt] = __builtin_amdgcn_mfma_f32_16x16x32_bf16(a[mt][ks], bf0[ks], acc0[mt], 0, 0, 0);
                acc1[mt] = __builtin_amdgcn_mfma_f32_16x16x32_bf16(a[mt][ks], bf1[ks], acc1[mt], 0, 0, 0);
            }

        // packed argmin: score' = (enorm+1) - 2*dot (always ~1.0 > 0),
        // clear low 10 mantissa bits, OR in code; u32 min == float min + tie-low.
        #pragma unroll
        for (int mt = 0; mt < 4; ++mt)
            #pragma unroll
            for (int r = 0; r < 4; ++r) {
                float s0 = fmaf(acc0[mt][r], -2.0f, en0);
                float s1 = fmaf(acc1[mt][r], -2.0f, en1);
                unsigned int u0 = (__float_as_uint(s0) & ~1023u) | code0;
                unsigned int u1 = (__float_as_uint(s1) & ~1023u) | (code0 + 16u);
                best[mt][r] = min(best[mt][r], min(u0, u1));
            }
        __syncthreads();   // chunk consumed by all waves; prefetch now visible
    }

    // in-wave reduce over the 16 code-columns (xor lanes 1,2,4,8 stay in quad)
    #pragma unroll
    for (int mt = 0; mt < 4; ++mt)
        #pragma unroll
        for (int r = 0; r < 4; ++r) {
            unsigned int v = best[mt][r];
            v = min(v, (unsigned int)__shfl_xor((int)v, 1));
            v = min(v, (unsigned int)__shfl_xor((int)v, 2));
            v = min(v, (unsigned int)__shfl_xor((int)v, 4));
            v = min(v, (unsigned int)__shfl_xor((int)v, 8));
            if (nn == 0) wbest[wn][wm * 64 + mt * 16 + q * 4 + r] = v;
        }
    __syncthreads();

    if (t < MB) {
        unsigned int v = min(wbest[0][t], wbest[1][t]);
        unsigned int code = v & 1023u;
        idxs[t] = (unsigned short)code;
        out[IDX_OFF + n0g + t] = (float)code;
    }
    __syncthreads();

    // epilogue: per-position emb gather, register transpose, float4 z_q
    // stores along pos, exact fp32 loss vs the bf16 zt values
    {
        const int pos4 = (t & 63) * 4;
        const int c0 = (t >> 6) * 16;
        float* og = out + ZQ_OFF + (size_t)b * C * HW + hw0;
        float ev[4][16];
        float ls = 0.f;
        #pragma unroll
        for (int j = 0; j < 4; ++j) {
            const int pos = pos4 + j;
            const float* erow = emb + (size_t)idxs[pos] * C;
            #pragma unroll
            for (int g = 0; g < 4; ++g) {
                float4 e = *(const float4*)&erow[c0 + g * 4];
                ev[j][g * 4 + 0] = e.x; ev[j][g * 4 + 1] = e.y;
                ev[j][g * 4 + 2] = e.z; ev[j][g * 4 + 3] = e.w;
            }
            const unsigned int row = (unsigned int)pos;
            const unsigned int sw = ((row >> 2) & 7u) << 4;
            const unsigned int base = row * RSB + c0 * 2;
            u16x8 z0 = *(u16x8*)(ztb + (base ^ sw));
            u16x8 z1 = *(u16x8*)(ztb + ((base + 16) ^ sw));
            #pragma unroll
            for (int i = 0; i < 8; ++i) {
                float zf0 = __uint_as_float((unsigned int)z0[i] << 16);
                float zf1 = __uint_as_float((unsigned int)z1[i] << 16);
                float d0 = zf0 - ev[j][i];
                float d1 = zf1 - ev[j][8 + i];
                ls += d0 * d0 + d1 * d1;
            }
        }
        #pragma unroll
        for (int i = 0; i < 16; ++i) {
            float4 v = { ev[0][i], ev[1][i], ev[2][i], ev[3][i] };
            *(float4*)&og[(size_t)(c0 + i) * HW + pos4] = v;
        }
        #pragma unroll
        for (int off = 32; off; off >>= 1) ls += __shfl_down(ls, off);
        if (lane == 0) lred[w] = ls;
    }
    __syncthreads();
    if (t == 0) {
        float bs = 0.f;
        #pragma unroll
        for (int i = 0; i < 8; ++i) bs += lred[i];
        atomicAdd(S, bs);
    }
}

__global__ void vq_final(const float* __restrict__ S, float* __restrict__ out) {
    float s = *S;
    out[LOSS_OFF] = 1.25f * s;
    out[COMMIT_OFF] = 0.25f * s;
    out[CODE_OFF] = s;
}

extern "C" void kernel_launch(void* const* d_in, const int* in_sizes, int n_in,
                              void* d_out, int out_size, void* d_ws, size_t ws_size,
                              hipStream_t stream) {
    const float* z = (const float*)d_in[0];
    const float* emb = (const float*)d_in[1];
    float* out = (float*)d_out;
    float* S = (float*)d_ws;
    unsigned char* img = (unsigned char*)d_ws + WS_IMG_OFF;   // needs ~287 KB of ws

    vq_prep<<<K, 64, 0, stream>>>(emb, img, S);
    vq_main<<<NBLK, 512, 0, stream>>>(z, emb, img, out, S);
    vq_final<<<1, 1, 0, stream>>>(S, out);
}

// Round 11
// 117.731 us; speedup vs baseline: 1.0069x; 1.0069x over previous
//
#include <hip/hip_runtime.h>
#include <hip/hip_bf16.h>

#define C 128
#define HW 4096
#define NPOS 65536
#define K 1024
#define MB 256           // positions per block
#define NBLK (NPOS/MB)   // 256 -> 1 block/CU
#define RS 136           // padded row stride in bf16 elems (272 B)
#define RSB 272          // row stride bytes
#define CHK 128          // codes per chunk (r11: 2x -> HALVES per-chunk overhead count)
#define NCH (K/CHK)      // 8
#define CHB (CHK*RSB)    // 34816 bytes per chunk

#define ZQ_OFF 0
#define LOSS_OFF 8388608
#define IDX_OFF 8388609
#define COMMIT_OFF 8454145
#define CODE_OFF 8454146

#define WS_IMG_OFF 8192  // bf16 codebook image at d_ws + 8192, 1024*272 B

typedef __bf16 bf16x8 __attribute__((ext_vector_type(8)));
typedef float f32x4 __attribute__((ext_vector_type(4)));
typedef unsigned short u16x8 __attribute__((ext_vector_type(8)));

// Padded bf16 codebook image: row k = 128 bf16 (272B stride),
// fp32 (||e_k||^2 + 1.0) at row byte offset 256. Block 0 zeroes the loss
// accumulator S[0] and the completion ticket S[1].
__global__ void vq_prep(const float* __restrict__ emb, unsigned char* __restrict__ img,
                        float* __restrict__ S) {
    int k = blockIdx.x;
    int l = threadIdx.x;            // 64 threads
    if (k == 0 && l == 0) { S[0] = 0.0f; ((unsigned int*)S)[1] = 0u; }
    float v0 = emb[k * C + l];
    float v1 = emb[k * C + 64 + l];
    __hip_bfloat16 h0 = __float2bfloat16(v0);
    __hip_bfloat16 h1 = __float2bfloat16(v1);
    unsigned short* row = (unsigned short*)(img + (size_t)k * RSB);
    row[l] = *(unsigned short*)&h0;
    row[64 + l] = *(unsigned short*)&h1;
    float s = v0 * v0 + v1 * v1;
    #pragma unroll
    for (int off = 32; off; off >>= 1) s += __shfl_down(s, off);
    if (l == 0) *(float*)(img + (size_t)k * RSB + 256) = s + 1.0f;
}

// MB=256, 512 thr / 8 waves (4M x 2N), grid 256 = 1 block/CU.
// r10 lesson: chunk-loop time is FIXED overhead per chunk (~3100 cyc:
// barrier convoy + prefetch drain), invariant to per-chunk work. So CHK=128:
// 8 chunks instead of 16 -> half the overhead events; per-chunk compute
// (~2400 cyc) now also covers the 34KB prefetch before the drain.
// LDS ~142 KB -> 1 block/CU -> 2 waves/EU -> VGPR budget 256 (r8/r9 rule),
// so the asm-pinned A fragments (64 VGPRs) stay resident, no spill.
// zt is LINEAR (r10's swizzle made conflicts worse; 272B odd stride is fine).
__global__ __launch_bounds__(512)
void vq_main(const float* __restrict__ z, const float* __restrict__ emb,
             const unsigned char* __restrict__ img,
             float* __restrict__ out, float* __restrict__ S) {
    __shared__ __align__(16) unsigned short zt[MB * RS];          // 69632 B
    __shared__ __align__(16) unsigned short bbuf[2][CHK * RS];    // 69632 B
    __shared__ unsigned int wbest[2][MB];                         // 2048 B
    __shared__ unsigned short idxs[MB];                           // 512 B
    __shared__ float lred[8];
    // total ~142 KB -> exactly 1 block/CU

    const int t = threadIdx.x;
    const int w = t >> 6;
    const int lane = t & 63;
    const int nn = lane & 15;      // MFMA: A row m / B col n / C col
    const int q = lane >> 4;       // quad
    const int wm = w >> 1;         // M-quarter: positions wm*64..+63
    const int wn = w & 1;          // N-half: codes wn*64..+63 of each chunk

    const int blk = blockIdx.x;
    const int n0g = blk * MB;
    const int b = n0g >> 12;
    const int hw0 = n0g & (HW - 1);
    const float* zg = z + (size_t)b * C * HW + hw0;

    // async stage chunk 0 (34 x 1KB split across 8 waves)
    for (int j = w; j < 34; j += 8) {
        __builtin_amdgcn_global_load_lds(
            (const __attribute__((address_space(1))) unsigned int*)(img + j * 1024 + lane * 16),
            (__attribute__((address_space(3))) unsigned int*)((unsigned char*)bbuf[0] + j * 1024),
            16, 0, 0);
    }

    // stage z tile -> LDS bf16 [pos][c]: float4 along pos, register transpose
    {
        const int pos4 = (t & 63) * 4;
        const int c0 = (t >> 6) * 16;
        float4 fv[16];
        #pragma unroll
        for (int i = 0; i < 16; ++i)
            fv[i] = *(const float4*)&zg[(size_t)(c0 + i) * HW + pos4];
        #pragma unroll
        for (int j = 0; j < 4; ++j) {
            u16x8 p0, p1;
            #pragma unroll
            for (int i = 0; i < 8; ++i) {
                float f0 = (j == 0) ? fv[i].x : (j == 1) ? fv[i].y
                         : (j == 2) ? fv[i].z : fv[i].w;
                float f1 = (j == 0) ? fv[8 + i].x : (j == 1) ? fv[8 + i].y
                         : (j == 2) ? fv[8 + i].z : fv[8 + i].w;
                __hip_bfloat16 h0 = __float2bfloat16(f0);
                __hip_bfloat16 h1 = __float2bfloat16(f1);
                p0[i] = *(unsigned short*)&h0;
                p1[i] = *(unsigned short*)&h1;
            }
            *(u16x8*)&zt[(pos4 + j) * RS + c0] = p0;
            *(u16x8*)&zt[(pos4 + j) * RS + c0 + 8] = p1;
        }
    }
    __syncthreads();   // covers zt ds_writes AND chunk-0 global_load_lds drain

    // A fragments: 4 M-tiles x 4 K-steps = 64 VGPRs, pinned resident
    bf16x8 a[4][4];
    #pragma unroll
    for (int mt = 0; mt < 4; ++mt)
        #pragma unroll
        for (int ks = 0; ks < 4; ++ks) {
            a[mt][ks] = *(bf16x8*)&zt[(wm * 64 + mt * 16 + nn) * RS + ks * 32 + q * 8];
            asm volatile("" : "+v"(*(f32x4*)&a[mt][ks]));
        }

    unsigned int best[4][4];
    #pragma unroll
    for (int mt = 0; mt < 4; ++mt)
        #pragma unroll
        for (int r = 0; r < 4; ++r) best[mt][r] = 0xFFFFFFFFu;

    for (int ch = 0; ch < NCH; ++ch) {
        const int p = ch & 1;
        if (ch + 1 < NCH) {   // prefetch next chunk into other buffer (early issue)
            const unsigned char* src = img + (size_t)(ch + 1) * CHB;
            for (int j = w; j < 34; j += 8) {
                __builtin_amdgcn_global_load_lds(
                    (const __attribute__((address_space(1))) unsigned int*)(src + j * 1024 + lane * 16),
                    (__attribute__((address_space(3))) unsigned int*)((unsigned char*)bbuf[p ^ 1] + j * 1024),
                    16, 0, 0);
            }
        }
        const unsigned short* bb = bbuf[p];

        // wave's 64 codes of this chunk, processed as 2 halves of 32
        // (caps transient VGPR: bf 32 + acc 32 at a time)
        #pragma unroll
        for (int half = 0; half < 2; ++half) {
            const int row0 = wn * 64 + half * 32 + nn;
            const int row1 = row0 + 16;
            bf16x8 bf0[4], bf1[4];
            #pragma unroll
            for (int ks = 0; ks < 4; ++ks) {
                bf0[ks] = *(const bf16x8*)&bb[row0 * RS + ks * 32 + q * 8];
                bf1[ks] = *(const bf16x8*)&bb[row1 * RS + ks * 32 + q * 8];
            }
            const float en0 = *(const float*)&bb[row0 * RS + 128];
            const float en1 = *(const float*)&bb[row1 * RS + 128];
            const unsigned int code0 = (unsigned int)(ch * CHK + wn * 64 + half * 32 + nn);

            f32x4 acc0[4], acc1[4];
            #pragma unroll
            for (int mt = 0; mt < 4; ++mt) {
                acc0[mt] = (f32x4){0.f, 0.f, 0.f, 0.f};
                acc1[mt] = (f32x4){0.f, 0.f, 0.f, 0.f};
            }
            #pragma unroll
            for (int ks = 0; ks < 4; ++ks)
                #pragma unroll
                for (int mt = 0; mt < 4; ++mt) {
                    acc0[mt] = __builtin_amdgcn_mfma_f32_16x16x32_bf16(a[mt][ks], bf0[ks], acc0[mt], 0, 0, 0);
                    acc1[mt] = __builtin_amdgcn_mfma_f32_16x16x32_bf16(a[mt][ks], bf1[ks], acc1[mt], 0, 0, 0);
                }

            // packed argmin: score' = (enorm+1) - 2*dot (always ~1.0 > 0),
            // clear low 10 mantissa bits, OR in code; u32 min == float min + tie-low.
            #pragma unroll
            for (int mt = 0; mt < 4; ++mt)
                #pragma unroll
                for (int r = 0; r < 4; ++r) {
                    float s0 = fmaf(acc0[mt][r], -2.0f, en0);
                    float s1 = fmaf(acc1[mt][r], -2.0f, en1);
                    unsigned int u0 = (__float_as_uint(s0) & ~1023u) | code0;
                    unsigned int u1 = (__float_as_uint(s1) & ~1023u) | (code0 + 16u);
                    best[mt][r] = min(best[mt][r], min(u0, u1));
                }
        }
        __syncthreads();   // chunk consumed by all waves; prefetch now visible
    }

    // in-wave reduce over the 16 code-columns (xor lanes 1,2,4,8 stay in quad)
    #pragma unroll
    for (int mt = 0; mt < 4; ++mt)
        #pragma unroll
        for (int r = 0; r < 4; ++r) {
            unsigned int v = best[mt][r];
            v = min(v, (unsigned int)__shfl_xor((int)v, 1));
            v = min(v, (unsigned int)__shfl_xor((int)v, 2));
            v = min(v, (unsigned int)__shfl_xor((int)v, 4));
            v = min(v, (unsigned int)__shfl_xor((int)v, 8));
            if (nn == 0) wbest[wn][wm * 64 + mt * 16 + q * 4 + r] = v;
        }
    __syncthreads();

    if (t < MB) {
        unsigned int v = min(wbest[0][t], wbest[1][t]);
        unsigned int code = v & 1023u;
        idxs[t] = (unsigned short)code;
        out[IDX_OFF + n0g + t] = (float)code;
    }
    __syncthreads();

    // epilogue: per-position emb gather, register transpose, float4 z_q
    // stores along pos, exact fp32 loss vs the bf16 zt values
    {
        const int pos4 = (t & 63) * 4;
        const int c0 = (t >> 6) * 16;
        float* og = out + ZQ_OFF + (size_t)b * C * HW + hw0;
        float ev[4][16];
        float ls = 0.f;
        #pragma unroll
        for (int j = 0; j < 4; ++j) {
            const int pos = pos4 + j;
            const float* erow = emb + (size_t)idxs[pos] * C;
            #pragma unroll
            for (int g = 0; g < 4; ++g) {
                float4 e = *(const float4*)&erow[c0 + g * 4];
                ev[j][g * 4 + 0] = e.x; ev[j][g * 4 + 1] = e.y;
                ev[j][g * 4 + 2] = e.z; ev[j][g * 4 + 3] = e.w;
            }
            u16x8 z0 = *(u16x8*)&zt[pos * RS + c0];
            u16x8 z1 = *(u16x8*)&zt[pos * RS + c0 + 8];
            #pragma unroll
            for (int i = 0; i < 8; ++i) {
                float zf0 = __uint_as_float((unsigned int)z0[i] << 16);
                float zf1 = __uint_as_float((unsigned int)z1[i] << 16);
                float d0 = zf0 - ev[j][i];
                float d1 = zf1 - ev[j][8 + i];
                ls += d0 * d0 + d1 * d1;
            }
        }
        #pragma unroll
        for (int i = 0; i < 16; ++i) {
            float4 v = { ev[0][i], ev[1][i], ev[2][i], ev[3][i] };
            *(float4*)&og[(size_t)(c0 + i) * HW + pos4] = v;
        }
        #pragma unroll
        for (int off = 32; off; off >>= 1) ls += __shfl_down(ls, off);
        if (lane == 0) lred[w] = ls;
    }
    __syncthreads();

    // fused finalization, NO fences (r2's regression was 512 device fences):
    // the asm consumes the S-add's return value (forces vmcnt wait) and its
    // "memory" clobber keeps the ticket add AFTER it -> each block's S-add is
    // complete in L2 before its ticket lands. Winner reads S via RMW on the
    // same cache line (atomics are device-scope coherent).
    if (t == 0) {
        float bs = 0.f;
        #pragma unroll
        for (int i = 0; i < 8; ++i) bs += lred[i];
        float prev = atomicAdd(S, bs);
        asm volatile("" :: "v"(prev) : "memory");
        unsigned int old = atomicAdd((unsigned int*)S + 1, 1u);
        if (old == NBLK - 1) {
            float s = atomicAdd(S, 0.0f);   // coherent RMW read of the total
            out[LOSS_OFF] = 1.25f * s;
            out[COMMIT_OFF] = 0.25f * s;
            out[CODE_OFF] = s;
        }
    }
}

extern "C" void kernel_launch(void* const* d_in, const int* in_sizes, int n_in,
                              void* d_out, int out_size, void* d_ws, size_t ws_size,
                              hipStream_t stream) {
    const float* z = (const float*)d_in[0];
    const float* emb = (const float*)d_in[1];
    float* out = (float*)d_out;
    float* S = (float*)d_ws;
    unsigned char* img = (unsigned char*)d_ws + WS_IMG_OFF;   // needs ~287 KB of ws

    vq_prep<<<K, 64, 0, stream>>>(emb, img, S);
    vq_main<<<NBLK, 512, 0, stream>>>(z, emb, img, out, S);
}